// Round 1
// baseline (5343.069 us; speedup 1.0000x reference)
//
#include <hip/hip_runtime.h>
#include <hip/hip_bf16.h>
#include <math.h>

// Problem constants
#define B_  32
#define L_  512
#define D_  768
#define H_  12
#define SD_ 5
#define DH_ 64
#define ML_ (B_ * L_)          // 16384 rows
#define CN_ (H_ * (SD_ + 1))   // 72 cond columns

// ---------------------------------------------------------------------------
// Generic fp32 tiled GEMM: C[M,N] = A[M,K] @ W[K,N] + bias[N] (+resid[M,N])
// Optional txt: A_eff[m,k] = A[m,k] + txt[(m>>9), k]  (broadcast over L=512)
// Tile 64x64, K-tile 16, 256 threads, 4x4 micro-tile per thread.
// M must be a multiple of 64 and K a multiple of 16 (true here: 16384, 768).
// ---------------------------------------------------------------------------
__global__ __launch_bounds__(256) void gemm_kernel(
    const float* __restrict__ A, const float* __restrict__ W,
    const float* __restrict__ bias, const float* resid,
    const float* txt, float* __restrict__ C,
    int M, int N, int K)
{
    __shared__ float As[16][65];   // [k][m], padded to kill store conflicts
    __shared__ float Bs[16][64];   // [k][n]

    const int tid = threadIdx.x;
    const int tx = tid & 15;       // 0..15  -> n micro
    const int ty = tid >> 4;       // 0..15  -> m micro
    const int m0 = blockIdx.y * 64;
    const int n0 = blockIdx.x * 64;

    const int la_m = tid >> 2;          // 0..63
    const int la_k = (tid & 3) * 4;     // 0,4,8,12
    const int lb_k = tid >> 4;          // 0..15
    const int lb_n = (tid & 15) * 4;    // 0..60

    float acc[4][4];
    #pragma unroll
    for (int i = 0; i < 4; ++i)
        #pragma unroll
        for (int j = 0; j < 4; ++j) acc[i][j] = 0.f;

    for (int k0 = 0; k0 < K; k0 += 16) {
        // A tile
        float4 av = *(const float4*)(A + (size_t)(m0 + la_m) * K + k0 + la_k);
        if (txt) {
            const float* trow = txt + (size_t)((m0 + la_m) >> 9) * K + k0 + la_k;
            av.x += trow[0]; av.y += trow[1]; av.z += trow[2]; av.w += trow[3];
        }
        As[la_k + 0][la_m] = av.x;
        As[la_k + 1][la_m] = av.y;
        As[la_k + 2][la_m] = av.z;
        As[la_k + 3][la_m] = av.w;
        // B tile (guard N for the cond GEMM, N=72)
        if (n0 + lb_n + 3 < N) {
            *(float4*)&Bs[lb_k][lb_n] =
                *(const float4*)(W + (size_t)(k0 + lb_k) * N + n0 + lb_n);
        } else {
            #pragma unroll
            for (int j = 0; j < 4; ++j)
                Bs[lb_k][lb_n + j] = (n0 + lb_n + j < N)
                    ? W[(size_t)(k0 + lb_k) * N + n0 + lb_n + j] : 0.f;
        }
        __syncthreads();

        #pragma unroll
        for (int kk = 0; kk < 16; ++kk) {
            float a[4], b[4];
            #pragma unroll
            for (int i = 0; i < 4; ++i) a[i] = As[kk][ty * 4 + i];
            #pragma unroll
            for (int j = 0; j < 4; ++j) b[j] = Bs[kk][tx * 4 + j];
            #pragma unroll
            for (int i = 0; i < 4; ++i)
                #pragma unroll
                for (int j = 0; j < 4; ++j) acc[i][j] += a[i] * b[j];
        }
        __syncthreads();
    }

    #pragma unroll
    for (int i = 0; i < 4; ++i) {
        const int m = m0 + ty * 4 + i;
        #pragma unroll
        for (int j = 0; j < 4; ++j) {
            const int n = n0 + tx * 4 + j;
            if (n < N) {
                float v = acc[i][j] + bias[n];
                if (resid) v += resid[(size_t)m * N + n];
                C[(size_t)m * N + n] = v;
            }
        }
    }
}

// ---------------------------------------------------------------------------
// Attention: one block per (b,l) row. Computes all H heads' logits, softmax,
// writes fused_attn [B,H,L,L] to d_out, accumulates PV context into ctx.
// ctx may alias qh (same row only; q-row is copied to LDS first).
// ---------------------------------------------------------------------------
__global__ __launch_bounds__(256) void attn_kernel(
    const float* qh, const float* __restrict__ kh,
    const float* __restrict__ vh, const float* __restrict__ sw,
    const float* __restrict__ pl, const int* __restrict__ mask,
    float* __restrict__ fused, float* ctx)
{
    const int bl = blockIdx.x;          // b*L + l
    const int b  = bl >> 9;
    const int l  = bl & 511;
    const int tid = threadIdx.x;

    __shared__ float qrow[D_];
    __shared__ float swrow[CN_];
    __shared__ float srow[H_ * L_];     // 6144 floats: logits -> probs
    __shared__ int   mrow[L_];

    for (int i = tid; i < D_; i += 256) qrow[i] = qh[(size_t)bl * D_ + i];
    if (tid < CN_) swrow[tid] = sw[(size_t)bl * CN_ + tid];
    for (int i = tid; i < L_; i += 256) mrow[i] = mask[b * L_ + i];
    __syncthreads();

    const size_t bbase = (size_t)b * L_ * D_;

    // Phase 1: logits
    for (int idx = tid; idx < H_ * L_; idx += 256) {
        const int h = idx >> 9;
        const int t = idx & 511;
        float logit;
        if (mrow[t]) {
            logit = -1e30f;
        } else {
            const float4* k4 = (const float4*)(kh + bbase + (size_t)t * D_ + h * DH_);
            const float4* q4 = (const float4*)(qrow + h * DH_);
            float dot = 0.f;
            #pragma unroll
            for (int j = 0; j < DH_ / 4; ++j) {
                float4 kv = k4[j], qv = q4[j];
                dot += kv.x * qv.x + kv.y * qv.y + kv.z * qv.z + kv.w * qv.w;
            }
            const float attn = dot * 0.125f;   // 1/sqrt(64)
            const float* p = pl + ((size_t)bl * L_ + t) * SD_;
            float lv = swrow[h * 6]
                     + swrow[h * 6 + 1] * p[0] + swrow[h * 6 + 2] * p[1]
                     + swrow[h * 6 + 3] * p[2] + swrow[h * 6 + 4] * p[3]
                     + swrow[h * 6 + 5] * p[4];
            float sig = 1.f / (1.f + expf(-lv));
            sig = fmaxf(sig, 1e-6f);
            logit = logf(sig) + attn;
        }
        srow[idx] = logit;
    }
    __syncthreads();

    // Phase 2: per-head softmax. 4 waves x 3 heads.
    const int wave = tid >> 6, lane = tid & 63;
    for (int h = wave * 3; h < wave * 3 + 3; ++h) {
        float v[8];
        float m = -1e30f;
        #pragma unroll
        for (int j = 0; j < 8; ++j) {
            v[j] = srow[h * L_ + lane + j * 64];
            m = fmaxf(m, v[j]);
        }
        #pragma unroll
        for (int off = 32; off >= 1; off >>= 1) m = fmaxf(m, __shfl_xor(m, off));
        float sum = 0.f;
        #pragma unroll
        for (int j = 0; j < 8; ++j) { v[j] = expf(v[j] - m); sum += v[j]; }
        #pragma unroll
        for (int off = 32; off >= 1; off >>= 1) sum += __shfl_xor(sum, off);
        const float inv = 1.f / sum;
        float* out = fused + (((size_t)b * H_ + h) * L_ + l) * L_;
        #pragma unroll
        for (int j = 0; j < 8; ++j) {
            const float pj = v[j] * inv;
            srow[h * L_ + lane + j * 64] = pj;
            out[lane + j * 64] = pj;
        }
    }
    __syncthreads();

    // Phase 3: PV. 768 outputs / 256 threads = 3 accumulators each.
    const int dh = tid & 63;
    const int ha = tid >> 6, hb = ha + 4, hc = ha + 8;
    float acc0 = 0.f, acc1 = 0.f, acc2 = 0.f;
    for (int t = 0; t < L_; ++t) {
        const float* vrow = vh + bbase + (size_t)t * D_;
        acc0 += srow[ha * L_ + t] * vrow[ha * DH_ + dh];
        acc1 += srow[hb * L_ + t] * vrow[hb * DH_ + dh];
        acc2 += srow[hc * L_ + t] * vrow[hc * DH_ + dh];
    }
    float* crow = ctx + (size_t)bl * D_;
    crow[ha * DH_ + dh] = acc0;
    crow[hb * DH_ + dh] = acc1;
    crow[hc * DH_ + dh] = acc2;
}

// ---------------------------------------------------------------------------
// LayerNorm: one block per row of 768.
// ---------------------------------------------------------------------------
__global__ __launch_bounds__(256) void ln_kernel(
    const float* __restrict__ x, const float* __restrict__ scale,
    const float* __restrict__ bias, float* __restrict__ y)
{
    const int row = blockIdx.x;
    const int tid = threadIdx.x;
    const float* xr = x + (size_t)row * D_;

    float v0 = xr[tid], v1 = xr[tid + 256], v2 = xr[tid + 512];
    float s = v0 + v1 + v2;
    #pragma unroll
    for (int off = 32; off >= 1; off >>= 1) s += __shfl_xor(s, off);

    __shared__ float red[4];
    __shared__ float red2[4];
    const int wave = tid >> 6, lane = tid & 63;
    if (lane == 0) red[wave] = s;
    __syncthreads();
    const float mu = (red[0] + red[1] + red[2] + red[3]) * (1.f / 768.f);

    const float d0 = v0 - mu, d1 = v1 - mu, d2 = v2 - mu;
    float sq = d0 * d0 + d1 * d1 + d2 * d2;
    #pragma unroll
    for (int off = 32; off >= 1; off >>= 1) sq += __shfl_xor(sq, off);
    if (lane == 0) red2[wave] = sq;
    __syncthreads();
    const float var = (red2[0] + red2[1] + red2[2] + red2[3]) * (1.f / 768.f);
    const float r = rsqrtf(var + 1e-5f);

    float* yr = y + (size_t)row * D_;
    yr[tid]       = d0 * r * scale[tid]       + bias[tid];
    yr[tid + 256] = d1 * r * scale[tid + 256] + bias[tid + 256];
    yr[tid + 512] = d2 * r * scale[tid + 512] + bias[tid + 512];
}

// ---------------------------------------------------------------------------
extern "C" void kernel_launch(void* const* d_in, const int* in_sizes, int n_in,
                              void* d_out, int out_size, void* d_ws, size_t ws_size,
                              hipStream_t stream) {
    const float* q    = (const float*)d_in[0];
    const float* k    = (const float*)d_in[1];
    const float* v    = (const float*)d_in[2];
    const float* pl   = (const float*)d_in[3];
    const float* txt  = (const float*)d_in[4];
    const int*   mask = (const int*)  d_in[5];
    const float* Wq   = (const float*)d_in[6];
    const float* bq   = (const float*)d_in[7];
    const float* Wk   = (const float*)d_in[8];
    const float* bk   = (const float*)d_in[9];
    const float* Wv   = (const float*)d_in[10];
    const float* bv   = (const float*)d_in[11];
    const float* Wfc  = (const float*)d_in[12];
    const float* bfc  = (const float*)d_in[13];
    const float* Wc   = (const float*)d_in[14];
    const float* bc   = (const float*)d_in[15];
    const float* lns  = (const float*)d_in[16];
    const float* lnb  = (const float*)d_in[17];

    const size_t NE = (size_t)ML_ * D_;      // 12,582,912
    float* qh  = (float*)d_ws;
    float* kh  = qh + NE;
    float* vh  = kh + NE;
    float* swb = vh + NE;                    // 16384*72

    float* y     = (float*)d_out;
    float* fused = y + NE;                   // [B,H,L,L]

    const dim3 blk(256);
    const dim3 gproj(D_ / 64, ML_ / 64);     // (12, 256)
    const dim3 gcond((CN_ + 63) / 64, ML_ / 64);

    gemm_kernel<<<gproj, blk, 0, stream>>>(q, Wq, bq, nullptr, nullptr, qh, ML_, D_, D_);
    gemm_kernel<<<gproj, blk, 0, stream>>>(k, Wk, bk, nullptr, nullptr, kh, ML_, D_, D_);
    gemm_kernel<<<gproj, blk, 0, stream>>>(v, Wv, bv, nullptr, nullptr, vh, ML_, D_, D_);
    gemm_kernel<<<gcond, blk, 0, stream>>>(q, Wc, bc, nullptr, txt, swb, ML_, CN_, D_);

    // ctx overwrites qh row-wise (safe: q-row staged to LDS before phase 3)
    attn_kernel<<<dim3(ML_), blk, 0, stream>>>(qh, kh, vh, swb, pl, mask, fused, qh);

    // x = ctx @ Wfc + bfc + q  -> reuse kh as x buffer
    gemm_kernel<<<gproj, blk, 0, stream>>>(qh, Wfc, bfc, q, nullptr, kh, ML_, D_, D_);

    ln_kernel<<<dim3(ML_), blk, 0, stream>>>(kh, lns, lnb, y);
}